// Round 1
// 281.502 us; speedup vs baseline: 1.0188x; 1.0188x over previous
//
#include <hip/hip_runtime.h>

// QuaternionLinear as one 4096^3 bf16 GEMM (B^T layout).
// Round 7: port from 128^2 3-stage cyclic (R6, 787 TF, sync-bound at the
// m97-structure ceiling) to the 256^2 8-phase counted-vmcnt template
// (T1+T2+T3+T4+T5): BM=BN=256, BK=64, 8 waves (2Mx4N), 128 KiB LDS
// double-buffer. Per tile: 4 phases, each {ds_read subtile || 1 half-tile
// DMA -> barrier -> setprio(1) -> 16 MFMA -> setprio(0) -> barrier}.
// B fully read in P0 (held in regs all tile) so B regions of the CURRENT
// buffer are DMA-writable from P2 on (tile t+2's B); A streams per-phase,
// so next tile's A goes into the OTHER buffer at P0/P1. End-of-tile wait
// is vmcnt(4): A(t+1) landed, B(t+2)'s 4 loads stay in flight across the
// barrier (never vmcnt(0) until the peeled tail).
// WAR safety: any wave issuing phase-p+1 DMA has passed B2(p), which all
// waves reach only after draining their phase-p ds_reads (lgkmcnt before
// MFMA before B2). asm "memory" barriers pin ds_reads/DMA on their side.
// Swizzle (rule #21, both-sides): stored chunk = logical chunk ^ (row&7);
// DMA dest linear, per-lane GLOBAL source pre-swizzled, ds_read applies
// the same XOR. 16 lanes/col-group spread over all 8 chunks -> ~2-way.

typedef __bf16 bf16x8 __attribute__((ext_vector_type(8)));
typedef float floatx4 __attribute__((ext_vector_type(4)));

constexpr int M = 4096;   // batch
constexpr int N = 4096;   // out_f * 4
constexpr int K = 4096;   // in_f * 4
constexpr int BM = 256, BN = 256, BK = 64;
constexpr int TILES = K / BK;   // 64

constexpr int CVT_BLOCKS = (M * K / 8) / 256;        // 8192: x fp32 -> bf16
constexpr int EXP_BLOCKS = (1024 * 1024 / 2) / 256;  // 2048: w -> signed Wbig

// s_waitcnt simm16: vm[3:0] | exp<<4 | lgkm<<8 | vm[5:4]<<14
#define WAIT_VM4 0x0F74   // vmcnt(4)
#define WAIT_VM0 0x0F70   // vmcnt(0)
#define BARRIER() asm volatile("s_barrier" ::: "memory")

// ---------- fused prep: x -> A (bf16), w -> Wbig (sign-expanded bf16) ----------
// Wbig rows (c order) per quaternion w=(r,i,j,k):
//   d=0: [+r,-i,-j,-k]  d=1: [+i,+r,+k,-j]  d=2: [+j,-k,+r,+i]  d=3: [+k,+j,-i,+r]
__global__ void prep_kernel(const float* __restrict__ x, const float* __restrict__ w,
                            __bf16* __restrict__ A, __bf16* __restrict__ Wb) {
    const int b = blockIdx.x;
    if (b < CVT_BLOCKS) {
        const size_t i = (size_t)b * 256 + threadIdx.x;   // 8 elems/thread
        const float4* xp = (const float4*)x;
        float4 a = xp[2 * i];
        float4 c = xp[2 * i + 1];
        bf16x8 v;
        v[0] = (__bf16)a.x; v[1] = (__bf16)a.y; v[2] = (__bf16)a.z; v[3] = (__bf16)a.w;
        v[4] = (__bf16)c.x; v[5] = (__bf16)c.y; v[6] = (__bf16)c.z; v[7] = (__bf16)c.w;
        *(bf16x8*)(A + 8 * i) = v;
    } else {
        const int idx = (b - CVT_BLOCKS) * 256 + threadIdx.x;  // quaternion PAIR index
        const int o  = idx >> 9;
        const int ip = (idx & 511) * 2;
        float4 q0 = ((const float4*)w)[o * 1024 + ip];
        float4 q1 = ((const float4*)w)[o * 1024 + ip + 1];
        __bf16* base = Wb + (size_t)(o * 4) * K + ip * 4;
        bf16x8 r;
        r[0] = (__bf16)q0.x; r[1] = (__bf16)(-q0.y); r[2] = (__bf16)(-q0.z); r[3] = (__bf16)(-q0.w);
        r[4] = (__bf16)q1.x; r[5] = (__bf16)(-q1.y); r[6] = (__bf16)(-q1.z); r[7] = (__bf16)(-q1.w);
        *(bf16x8*)(base) = r;
        r[0] = (__bf16)q0.y; r[1] = (__bf16)q0.x; r[2] = (__bf16)q0.w; r[3] = (__bf16)(-q0.z);
        r[4] = (__bf16)q1.y; r[5] = (__bf16)q1.x; r[6] = (__bf16)q1.w; r[7] = (__bf16)(-q1.z);
        *(bf16x8*)(base + (size_t)K) = r;
        r[0] = (__bf16)q0.z; r[1] = (__bf16)(-q0.w); r[2] = (__bf16)q0.x; r[3] = (__bf16)q0.y;
        r[4] = (__bf16)q1.z; r[5] = (__bf16)(-q1.w); r[6] = (__bf16)q1.x; r[7] = (__bf16)q1.y;
        *(bf16x8*)(base + (size_t)2 * K) = r;
        r[0] = (__bf16)q0.w; r[1] = (__bf16)q0.z; r[2] = (__bf16)(-q0.y); r[3] = (__bf16)q0.x;
        r[4] = (__bf16)q1.w; r[5] = (__bf16)q1.z; r[6] = (__bf16)(-q1.y); r[7] = (__bf16)q1.x;
        *(bf16x8*)(base + (size_t)3 * K) = r;
    }
}

// ---------- async global->LDS, 16B per lane ----------
__device__ __forceinline__ void gload_lds16(const __bf16* g, __bf16* l) {
    __builtin_amdgcn_global_load_lds(
        (const __attribute__((address_space(1))) void*)g,
        (__attribute__((address_space(3))) void*)l, 16, 0, 0);
}

// ---------- GEMM: C[M][N] = A[M][K] * B[N][K]^T + bias[N] ----------
__global__ __launch_bounds__(512) void qgemm_kernel(const __bf16* __restrict__ A,
                                                    const __bf16* __restrict__ B,
                                                    const float* __restrict__ bias,
                                                    float* __restrict__ C) {
    __shared__ __bf16 As[2][BM][BK];   // 2 x 32 KiB
    __shared__ __bf16 Bs[2][BN][BK];   // 2 x 32 KiB  (128 KiB total -> 1 block/CU)

    const int tid  = threadIdx.x;
    const int wave = tid >> 6;          // 0..7
    const int lane = tid & 63;

    // Bijective XCD remap: 16x16 tile grid; each XCD owns an 8Mx4N region.
    const int bid = blockIdx.x;
    const int xcd = bid & 7;
    const int q   = bid >> 3;                       // 0..31
    const int tm  = (xcd >> 2) * 8 + (q & 7);       // 0..15
    const int tn  = (xcd & 3) * 4 + (q >> 3);       // 0..15
    const int bm  = tm * BM;
    const int bn  = tn * BN;

    const int wm = (wave >> 2) * 128;   // wave_m in {0,1} -> 128-row half
    const int wn = (wave & 3) * 64;     // wave_n in 0..3  -> 64-col slice

    // ---- staging addressing (per wave: 16-row stripe per half, 2 issues) ----
    // lane l writes LDS (row base + l>>3, chunk l&7); source chunk pre-swizzled
    // by (l>>3) == row&7 so that stored chunk s of row r holds global chunk
    // s ^ (r&7).
    const int srow = wave * 16 + (lane >> 3);              // 0..127 within half
    const int schk = ((lane & 7) ^ (lane >> 3)) * 8;       // pre-swizzled source
    const __bf16* agA = A + (size_t)(bm + srow) * K + schk;
    const __bf16* agB = B + (size_t)(bn + srow) * K + schk;

    auto issueA = [&](int buf, int h, int t) {
        const __bf16* g = agA + (size_t)h * 128 * K + t * BK;
        gload_lds16(g,                 &As[buf][h * 128 + wave * 16][0]);
        gload_lds16(g + (size_t)8 * K, &As[buf][h * 128 + wave * 16 + 8][0]);
    };
    auto issueB = [&](int buf, int h, int t) {
        const __bf16* g = agB + (size_t)h * 128 * K + t * BK;
        gload_lds16(g,                 &Bs[buf][h * 128 + wave * 16][0]);
        gload_lds16(g + (size_t)8 * K, &Bs[buf][h * 128 + wave * 16 + 8][0]);
    };

    // ---- fragment read addressing ----
    const int fl  = lane & 15;          // row-in-frag (A: m row, B: n col)
    const int fq  = lane >> 4;          // logical 16B chunk within k-slice
    const int fx7 = fl & 7;
    const int eo0 = (fq ^ fx7) * 8;         // ks=0: logical chunk fq
    const int eo1 = ((4 + fq) ^ fx7) * 8;   // ks=1: logical chunk 4+fq

    floatx4 acc[8][4] = {};
    bf16x8 bF[4][2];                    // all B frags for current tile

    // ---- prologue: tile0 A+B, tile1 B ----
    issueA(0, 0, 0); issueA(0, 1, 0);
    issueB(0, 0, 0); issueB(0, 1, 0);
    issueB(1, 0, 1); issueB(1, 1, 1);
    __builtin_amdgcn_s_waitcnt(WAIT_VM4);   // tile0's 8 loads landed; tile1 B in flight
    BARRIER();

    for (int t = 0; t < TILES; ++t) {
        const int b = t & 1;
#pragma unroll
        for (int p = 0; p < 4; ++p) {
            // A m-pair for this phase (stored-swizzled reads)
            bf16x8 aL0 = *(const bf16x8*)&As[b][wm + (2 * p) * 16 + fl][eo0];
            bf16x8 aL1 = *(const bf16x8*)&As[b][wm + (2 * p) * 16 + fl][eo1];
            bf16x8 aH0 = *(const bf16x8*)&As[b][wm + (2 * p + 1) * 16 + fl][eo0];
            bf16x8 aH1 = *(const bf16x8*)&As[b][wm + (2 * p + 1) * 16 + fl][eo1];
            if (p == 0) {               // all B frags, once per tile
#pragma unroll
                for (int nt = 0; nt < 4; ++nt) {
                    bF[nt][0] = *(const bf16x8*)&Bs[b][wn + nt * 16 + fl][eo0];
                    bF[nt][1] = *(const bf16x8*)&Bs[b][wn + nt * 16 + fl][eo1];
                }
            }
            // one half-tile DMA per phase
            if (p == 0 && t + 1 < TILES) issueA(b ^ 1, 0, t + 1);
            if (p == 1 && t + 1 < TILES) issueA(b ^ 1, 1, t + 1);
            if (p == 2 && t + 2 < TILES) issueB(b, 0, t + 2);
            if (p == 3 && t + 2 < TILES) issueB(b, 1, t + 2);
            BARRIER();
            __builtin_amdgcn_s_setprio(1);
#pragma unroll
            for (int nt = 0; nt < 4; ++nt) {
                acc[2 * p][nt]     = __builtin_amdgcn_mfma_f32_16x16x32_bf16(
                    aL0, bF[nt][0], acc[2 * p][nt], 0, 0, 0);
                acc[2 * p + 1][nt] = __builtin_amdgcn_mfma_f32_16x16x32_bf16(
                    aH0, bF[nt][0], acc[2 * p + 1][nt], 0, 0, 0);
                acc[2 * p][nt]     = __builtin_amdgcn_mfma_f32_16x16x32_bf16(
                    aL1, bF[nt][1], acc[2 * p][nt], 0, 0, 0);
                acc[2 * p + 1][nt] = __builtin_amdgcn_mfma_f32_16x16x32_bf16(
                    aH1, bF[nt][1], acc[2 * p + 1][nt], 0, 0, 0);
            }
            __builtin_amdgcn_s_setprio(0);
            if (p == 3) {
                if (t + 2 < TILES) __builtin_amdgcn_s_waitcnt(WAIT_VM4); // A(t+1) landed
                else               __builtin_amdgcn_s_waitcnt(WAIT_VM0); // peeled tail drain
            }
            BARRIER();
        }
    }

    // epilogue: C/D layout col = lane&15, row = (lane>>4)*4 + reg (verified R1)
#pragma unroll
    for (int mt = 0; mt < 8; ++mt) {
        const int row = bm + wm + mt * 16 + fq * 4;
#pragma unroll
        for (int nt = 0; nt < 4; ++nt) {
            const int col = bn + wn + nt * 16 + fl;
            const float bv = bias[col];
            float* cp = C + (size_t)row * N + col;
#pragma unroll
            for (int r = 0; r < 4; ++r)
                cp[(size_t)r * N] = acc[mt][nt][r] + bv;
        }
    }
}

extern "C" void kernel_launch(void* const* d_in, const int* in_sizes, int n_in,
                              void* d_out, int out_size, void* d_ws, size_t ws_size,
                              hipStream_t stream) {
    const float* x    = (const float*)d_in[0];   // (4096,1024,4) fp32
    const float* w    = (const float*)d_in[1];   // (1024,1024,4) fp32
    const float* bias = (const float*)d_in[2];   // (1024,4) fp32
    float* out = (float*)d_out;                  // (4096,1024,4) fp32

    __bf16* Abf  = (__bf16*)d_ws;                                   // 32 MB
    __bf16* Wbig = (__bf16*)((char*)d_ws + (size_t)M * K * 2);      // 32 MB

    prep_kernel<<<CVT_BLOCKS + EXP_BLOCKS, 256, 0, stream>>>(x, w, Abf, Wbig);

    qgemm_kernel<<<256, 512, 0, stream>>>(Abf, Wbig, bias, out);
}

// Round 2
// 250.963 us; speedup vs baseline: 1.1428x; 1.1217x over previous
//
#include <hip/hip_runtime.h>

// QuaternionLinear as one 4096^3 bf16 GEMM (B^T layout).
// Round 8: R7's 256^2 4-phase/tile counted-vmcnt structure, with WAITCNT
// CONTROL TAKEN FROM THE COMPILER. Theory: SIInsertWaitcnts cannot prove
// C++ ds_reads disjoint from in-flight global_load_lds DMA (runtime buffer
// index) and inserts conservative vmcnt drains before every phase's LDS
// reads -> ~700 cyc/phase stall, MfmaUtil pinned at ~34% in both R6 and R7.
// Fix (HK pattern): inline-asm ds_read_b128 on precomputed 32-bit LDS
// offsets (the waitcnt pass does not guard asm reads), manual
// "s_waitcnt lgkmcnt(0)" after each leading barrier + sched_barrier(0)
// (rule #18: MFMA builtins hoist past asm waits), manual per-tile
// "s_waitcnt vmcnt(4)" (never 0 until the peeled tail).
// Schedule per tile t (buf b=t&1): p0 reads all B frags + A m-pair 0 and
// issues BOTH A(t+1) halves into buf b^1 (3-phase slack); p2/p3 issue
// B(t+2) halves into buf b (B-region dead after p0's lgkm drain).
// WAR safety: every region a DMA targets had its readers lgkm-drained
// before that phase's leading barrier, which all waves cross before the
// issuing wave proceeds. vmcnt(4) at p3-end = B(t+1)+A(t+1) landed,
// B(t+2) (4 loads) stays in flight across the tile boundary.
// Swizzle (rule #21 both-sides): stored 16B chunk = logical chunk ^
// (row&7); DMA dest linear, per-lane GLOBAL source pre-swizzled, asm
// ds_read applies the same XOR. Measured 0 bank conflicts in R7.

typedef __bf16 bf16x8 __attribute__((ext_vector_type(8)));
typedef float floatx4 __attribute__((ext_vector_type(4)));

constexpr int M = 4096;   // batch
constexpr int N = 4096;   // out_f * 4
constexpr int K = 4096;   // in_f * 4
constexpr int BM = 256, BN = 256, BK = 64;
constexpr int TILES = K / BK;   // 64

constexpr int CVT_BLOCKS = (M * K / 8) / 256;        // 8192: x fp32 -> bf16
constexpr int EXP_BLOCKS = (1024 * 1024 / 2) / 256;  // 2048: w -> signed Wbig

#define BARRIER() asm volatile("s_barrier" ::: "memory")
#define LDS_OFF(p) ((unsigned)(uintptr_t)(__attribute__((address_space(3))) const void*)(p))

// ---------- fused prep: x -> A (bf16), w -> Wbig (sign-expanded bf16) ----------
// Wbig rows (c order) per quaternion w=(r,i,j,k):
//   d=0: [+r,-i,-j,-k]  d=1: [+i,+r,+k,-j]  d=2: [+j,-k,+r,+i]  d=3: [+k,+j,-i,+r]
__global__ void prep_kernel(const float* __restrict__ x, const float* __restrict__ w,
                            __bf16* __restrict__ A, __bf16* __restrict__ Wb) {
    const int b = blockIdx.x;
    if (b < CVT_BLOCKS) {
        const size_t i = (size_t)b * 256 + threadIdx.x;   // 8 elems/thread
        const float4* xp = (const float4*)x;
        float4 a = xp[2 * i];
        float4 c = xp[2 * i + 1];
        bf16x8 v;
        v[0] = (__bf16)a.x; v[1] = (__bf16)a.y; v[2] = (__bf16)a.z; v[3] = (__bf16)a.w;
        v[4] = (__bf16)c.x; v[5] = (__bf16)c.y; v[6] = (__bf16)c.z; v[7] = (__bf16)c.w;
        *(bf16x8*)(A + 8 * i) = v;
    } else {
        const int idx = (b - CVT_BLOCKS) * 256 + threadIdx.x;  // quaternion PAIR index
        const int o  = idx >> 9;
        const int ip = (idx & 511) * 2;
        float4 q0 = ((const float4*)w)[o * 1024 + ip];
        float4 q1 = ((const float4*)w)[o * 1024 + ip + 1];
        __bf16* base = Wb + (size_t)(o * 4) * K + ip * 4;
        bf16x8 r;
        r[0] = (__bf16)q0.x; r[1] = (__bf16)(-q0.y); r[2] = (__bf16)(-q0.z); r[3] = (__bf16)(-q0.w);
        r[4] = (__bf16)q1.x; r[5] = (__bf16)(-q1.y); r[6] = (__bf16)(-q1.z); r[7] = (__bf16)(-q1.w);
        *(bf16x8*)(base) = r;
        r[0] = (__bf16)q0.y; r[1] = (__bf16)q0.x; r[2] = (__bf16)q0.w; r[3] = (__bf16)(-q0.z);
        r[4] = (__bf16)q1.y; r[5] = (__bf16)q1.x; r[6] = (__bf16)q1.w; r[7] = (__bf16)(-q1.z);
        *(bf16x8*)(base + (size_t)K) = r;
        r[0] = (__bf16)q0.z; r[1] = (__bf16)(-q0.w); r[2] = (__bf16)q0.x; r[3] = (__bf16)q0.y;
        r[4] = (__bf16)q1.z; r[5] = (__bf16)(-q1.w); r[6] = (__bf16)q1.x; r[7] = (__bf16)q1.y;
        *(bf16x8*)(base + (size_t)2 * K) = r;
        r[0] = (__bf16)q0.w; r[1] = (__bf16)q0.z; r[2] = (__bf16)(-q0.y); r[3] = (__bf16)q0.x;
        r[4] = (__bf16)q1.w; r[5] = (__bf16)q1.z; r[6] = (__bf16)(-q1.y); r[7] = (__bf16)q1.x;
        *(bf16x8*)(base + (size_t)3 * K) = r;
    }
}

// ---------- async global->LDS, 16B per lane ----------
__device__ __forceinline__ void gload_lds16(const __bf16* g, __bf16* l) {
    __builtin_amdgcn_global_load_lds(
        (const __attribute__((address_space(1))) void*)g,
        (__attribute__((address_space(3))) void*)l, 16, 0, 0);
}

// ---------- manual ds_read_b128 (invisible to SIInsertWaitcnts) ----------
__device__ __forceinline__ bf16x8 dsr128(unsigned addr) {
    bf16x8 r;
    asm volatile("ds_read_b128 %0, %1" : "=v"(r) : "v"(addr));
    return r;
}

// ---------- GEMM: C[M][N] = A[M][K] * B[N][K]^T + bias[N] ----------
__global__ __launch_bounds__(512, 2) void qgemm_kernel(const __bf16* __restrict__ A,
                                                       const __bf16* __restrict__ B,
                                                       const float* __restrict__ bias,
                                                       float* __restrict__ C) {
    __shared__ __bf16 As[2][BM][BK];   // 2 x 32 KiB
    __shared__ __bf16 Bs[2][BN][BK];   // 2 x 32 KiB  (128 KiB total -> 1 block/CU)

    const int tid  = threadIdx.x;
    const int wave = tid >> 6;          // 0..7
    const int lane = tid & 63;

    // Bijective XCD remap: 16x16 tile grid; each XCD owns an 8Mx4N region.
    const int bid = blockIdx.x;
    const int xcd = bid & 7;
    const int q   = bid >> 3;                       // 0..31
    const int tm  = (xcd >> 2) * 8 + (q & 7);       // 0..15
    const int tn  = (xcd & 3) * 4 + (q >> 3);       // 0..15
    const int bm  = tm * BM;
    const int bn  = tn * BN;

    const int wm = (wave >> 2) * 128;   // wave_m in {0,1} -> 128-row half
    const int wn = (wave & 3) * 64;     // wave_n in 0..3  -> 64-col slice

    // ---- staging addressing (per wave: 16-row stripe per half, 2 issues) ----
    // lane l writes LDS (row base + l>>3, chunk l&7); source chunk pre-swizzled
    // by (l>>3)&7 == row&7 so stored chunk s of row r holds global chunk s^(r&7).
    const int srow = wave * 16 + (lane >> 3);              // 0..127 within half
    const int schk = ((lane & 7) ^ (lane >> 3)) * 8;       // pre-swizzled source
    const __bf16* agA = A + (size_t)(bm + srow) * K + schk;
    const __bf16* agB = B + (size_t)(bn + srow) * K + schk;

    auto issueA = [&](int buf, int h, int t) {
        const __bf16* g = agA + (size_t)h * 128 * K + t * BK;
        gload_lds16(g,                 &As[buf][h * 128 + wave * 16][0]);
        gload_lds16(g + (size_t)8 * K, &As[buf][h * 128 + wave * 16 + 8][0]);
    };
    auto issueB = [&](int buf, int h, int t) {
        const __bf16* g = agB + (size_t)h * 128 * K + t * BK;
        gload_lds16(g,                 &Bs[buf][h * 128 + wave * 16][0]);
        gload_lds16(g + (size_t)8 * K, &Bs[buf][h * 128 + wave * 16 + 8][0]);
    };

    // ---- fragment read addressing (32-bit LDS byte offsets) ----
    const int fl  = lane & 15;          // row-in-frag (A: m row, B: n col)
    const int fq  = lane >> 4;          // logical 16B chunk within k-slice
    const int fx7 = fl & 7;
    const unsigned ebo0 = (unsigned)(((fq)     ^ fx7) * 16);  // ks=0 byte offset
    const unsigned ebo1 = (unsigned)(((4 + fq) ^ fx7) * 16);  // ks=1 byte offset
    // row stride = BK*2 = 128 B; buffer stride = 256*128 = 32768 B
    const unsigned aRow = LDS_OFF(&As[0][0][0]) + (unsigned)(wm + fl) * 128u;
    const unsigned bRow = LDS_OFF(&Bs[0][0][0]) + (unsigned)(wn + fl) * 128u;

    floatx4 acc[8][4] = {};
    bf16x8 bF[4][2];                    // all B frags for current tile

    // ---- prologue: tile0 A+B, tile1 B ----
    issueA(0, 0, 0); issueA(0, 1, 0);
    issueB(0, 0, 0); issueB(0, 1, 0);
    issueB(1, 0, 1); issueB(1, 1, 1);
    asm volatile("s_waitcnt vmcnt(4)"); // tile0's 8 loads landed; tile1 B in flight
    BARRIER();

    for (int t = 0; t < TILES; ++t) {
        const int b  = t & 1;
        const unsigned bs = (unsigned)b * 32768u;
#pragma unroll
        for (int p = 0; p < 4; ++p) {
            const unsigned pa = bs + (unsigned)(p * 4096);   // p*32 rows * 128 B
            // A m-pair for this phase (swizzled asm reads)
            bf16x8 aL0 = dsr128(aRow + pa + ebo0);
            bf16x8 aL1 = dsr128(aRow + pa + ebo1);
            bf16x8 aH0 = dsr128(aRow + pa + 2048u + ebo0);
            bf16x8 aH1 = dsr128(aRow + pa + 2048u + ebo1);
            if (p == 0) {               // all B frags, once per tile
#pragma unroll
                for (int nt = 0; nt < 4; ++nt) {
                    bF[nt][0] = dsr128(bRow + bs + (unsigned)(nt * 2048) + ebo0);
                    bF[nt][1] = dsr128(bRow + bs + (unsigned)(nt * 2048) + ebo1);
                }
            }
            // staging: both A(t+1) halves at p0 (3-phase slack), B(t+2) at p2/p3
            if (p == 0 && t + 1 < TILES) { issueA(b ^ 1, 0, t + 1); issueA(b ^ 1, 1, t + 1); }
            if (p == 2 && t + 2 < TILES) issueB(b, 0, t + 2);
            if (p == 3 && t + 2 < TILES) issueB(b, 1, t + 2);
            BARRIER();
            asm volatile("s_waitcnt lgkmcnt(0)");
            __builtin_amdgcn_sched_barrier(0);   // rule #18: pin MFMA below the wait
            __builtin_amdgcn_s_setprio(1);
#pragma unroll
            for (int nt = 0; nt < 4; ++nt) {     // ks=0: 8 independent MFMAs
                acc[2 * p][nt]     = __builtin_amdgcn_mfma_f32_16x16x32_bf16(
                    aL0, bF[nt][0], acc[2 * p][nt], 0, 0, 0);
                acc[2 * p + 1][nt] = __builtin_amdgcn_mfma_f32_16x16x32_bf16(
                    aH0, bF[nt][0], acc[2 * p + 1][nt], 0, 0, 0);
            }
#pragma unroll
            for (int nt = 0; nt < 4; ++nt) {     // ks=1
                acc[2 * p][nt]     = __builtin_amdgcn_mfma_f32_16x16x32_bf16(
                    aL1, bF[nt][1], acc[2 * p][nt], 0, 0, 0);
                acc[2 * p + 1][nt] = __builtin_amdgcn_mfma_f32_16x16x32_bf16(
                    aH1, bF[nt][1], acc[2 * p + 1][nt], 0, 0, 0);
            }
            __builtin_amdgcn_s_setprio(0);
            if (p == 3) {
                if (t + 2 < TILES) asm volatile("s_waitcnt vmcnt(4)"); // A(t+1),B(t+1) landed
                else               asm volatile("s_waitcnt vmcnt(0)"); // peeled tail drain
            }
            BARRIER();
        }
    }

    // epilogue: C/D layout col = lane&15, row = (lane>>4)*4 + reg (verified R1)
#pragma unroll
    for (int mt = 0; mt < 8; ++mt) {
        const int row = bm + wm + mt * 16 + fq * 4;
#pragma unroll
        for (int nt = 0; nt < 4; ++nt) {
            const int col = bn + wn + nt * 16 + fl;
            const float bv = bias[col];
            float* cp = C + (size_t)row * N + col;
#pragma unroll
            for (int r = 0; r < 4; ++r)
                cp[(size_t)r * N] = acc[mt][nt][r] + bv;
        }
    }
}

extern "C" void kernel_launch(void* const* d_in, const int* in_sizes, int n_in,
                              void* d_out, int out_size, void* d_ws, size_t ws_size,
                              hipStream_t stream) {
    const float* x    = (const float*)d_in[0];   // (4096,1024,4) fp32
    const float* w    = (const float*)d_in[1];   // (1024,1024,4) fp32
    const float* bias = (const float*)d_in[2];   // (1024,4) fp32
    float* out = (float*)d_out;                  // (4096,1024,4) fp32

    __bf16* Abf  = (__bf16*)d_ws;                                   // 32 MB
    __bf16* Wbig = (__bf16*)((char*)d_ws + (size_t)M * K * 2);      // 32 MB

    prep_kernel<<<CVT_BLOCKS + EXP_BLOCKS, 256, 0, stream>>>(x, w, Abf, Wbig);

    qgemm_kernel<<<256, 512, 0, stream>>>(Abf, Wbig, bias, out);
}

// Round 3
// 247.536 us; speedup vs baseline: 1.1586x; 1.0138x over previous
//
#include <hip/hip_runtime.h>

// QuaternionLinear as one 4096^3 bf16 GEMM (B^T layout).
// Round 9: R8 (manual waitcnt, 1042 TF) still paid ~616 cyc/phase of
// structural overhead: per-phase barriers force {read issue -> join ->
// exposed lgkm latency -> MFMA} serialization, 8 joins/tile, LDS pipe
// never overlapped with MFMA (1 block/CU = no other waves to fill).
// Fix: 2 barriers per TILE (not 8) + software-pipelined A-fragment reads
// one phase ahead, so each phase's ds_reads complete under the previous
// phase's ~620-cyc MFMA shadow.
// Per tile t (buf b=t&1):
//   [reads: all 8 B frags + A p0 frags] [issue A(t+1) DMA -> buf b^1]
//   lgkm(0); BARRIER#1   // publishes: every wave drained Bs[b] reads
//   [issue B(t+2) DMA -> Bs[b]]        // only intra-tile hazard, now safe
//   p0: prefetch A(p1) || MFMA p0 ... p3: MFMA p3 (reads hidden)
//   vmcnt(4)  // A(t+1)+B(t+1) landed; B(t+2) stays in flight
//   BARRIER#2 // publishes DMA completions cross-wave (vmcnt is per-wave)
// WAR ledger: A(t+1)->As[b^1]: its readers (tile t-1) drained lgkm before
// t-1's BARRIER#2, which precedes this issue. B(t+2)->Bs[b]: readers
// drained before BARRIER#1. vmcnt per wave: enter tile with B(t+1) 4 in
// flight; +4 A(t+1); +4 B(t+2); vmcnt(4) drains the 8 needed for t+1.
// t=TILES-2 issues no B -> vmcnt(0). Swizzle + addressing identical to R8
// (verified, 0 bank conflicts). sched_barrier(0) fences pin every asm
// wait/read against MFMA-builtin motion (rule #18).

typedef __bf16 bf16x8 __attribute__((ext_vector_type(8)));
typedef float floatx4 __attribute__((ext_vector_type(4)));

constexpr int M = 4096;   // batch
constexpr int N = 4096;   // out_f * 4
constexpr int K = 4096;   // in_f * 4
constexpr int BM = 256, BN = 256, BK = 64;
constexpr int TILES = K / BK;   // 64

constexpr int CVT_BLOCKS = (M * K / 8) / 256;        // 8192: x fp32 -> bf16
constexpr int EXP_BLOCKS = (1024 * 1024 / 2) / 256;  // 2048: w -> signed Wbig

#define BARRIER() asm volatile("s_barrier" ::: "memory")
#define LGKM0()   do { asm volatile("s_waitcnt lgkmcnt(0)"); __builtin_amdgcn_sched_barrier(0); } while (0)
#define SB()      __builtin_amdgcn_sched_barrier(0)
#define LDS_OFF(p) ((unsigned)(uintptr_t)(__attribute__((address_space(3))) const void*)(p))

// ---------- fused prep: x -> A (bf16), w -> Wbig (sign-expanded bf16) ----------
// Wbig rows (c order) per quaternion w=(r,i,j,k):
//   d=0: [+r,-i,-j,-k]  d=1: [+i,+r,+k,-j]  d=2: [+j,-k,+r,+i]  d=3: [+k,+j,-i,+r]
__global__ void prep_kernel(const float* __restrict__ x, const float* __restrict__ w,
                            __bf16* __restrict__ A, __bf16* __restrict__ Wb) {
    const int b = blockIdx.x;
    if (b < CVT_BLOCKS) {
        const size_t i = (size_t)b * 256 + threadIdx.x;   // 8 elems/thread
        const float4* xp = (const float4*)x;
        float4 a = xp[2 * i];
        float4 c = xp[2 * i + 1];
        bf16x8 v;
        v[0] = (__bf16)a.x; v[1] = (__bf16)a.y; v[2] = (__bf16)a.z; v[3] = (__bf16)a.w;
        v[4] = (__bf16)c.x; v[5] = (__bf16)c.y; v[6] = (__bf16)c.z; v[7] = (__bf16)c.w;
        *(bf16x8*)(A + 8 * i) = v;
    } else {
        const int idx = (b - CVT_BLOCKS) * 256 + threadIdx.x;  // quaternion PAIR index
        const int o  = idx >> 9;
        const int ip = (idx & 511) * 2;
        float4 q0 = ((const float4*)w)[o * 1024 + ip];
        float4 q1 = ((const float4*)w)[o * 1024 + ip + 1];
        __bf16* base = Wb + (size_t)(o * 4) * K + ip * 4;
        bf16x8 r;
        r[0] = (__bf16)q0.x; r[1] = (__bf16)(-q0.y); r[2] = (__bf16)(-q0.z); r[3] = (__bf16)(-q0.w);
        r[4] = (__bf16)q1.x; r[5] = (__bf16)(-q1.y); r[6] = (__bf16)(-q1.z); r[7] = (__bf16)(-q1.w);
        *(bf16x8*)(base) = r;
        r[0] = (__bf16)q0.y; r[1] = (__bf16)q0.x; r[2] = (__bf16)q0.w; r[3] = (__bf16)(-q0.z);
        r[4] = (__bf16)q1.y; r[5] = (__bf16)q1.x; r[6] = (__bf16)q1.w; r[7] = (__bf16)(-q1.z);
        *(bf16x8*)(base + (size_t)K) = r;
        r[0] = (__bf16)q0.z; r[1] = (__bf16)(-q0.w); r[2] = (__bf16)q0.x; r[3] = (__bf16)q0.y;
        r[4] = (__bf16)q1.z; r[5] = (__bf16)(-q1.w); r[6] = (__bf16)q1.x; r[7] = (__bf16)q1.y;
        *(bf16x8*)(base + (size_t)2 * K) = r;
        r[0] = (__bf16)q0.w; r[1] = (__bf16)q0.z; r[2] = (__bf16)(-q0.y); r[3] = (__bf16)q0.x;
        r[4] = (__bf16)q1.w; r[5] = (__bf16)q1.z; r[6] = (__bf16)(-q1.y); r[7] = (__bf16)q1.x;
        *(bf16x8*)(base + (size_t)3 * K) = r;
    }
}

// ---------- async global->LDS, 16B per lane ----------
__device__ __forceinline__ void gload_lds16(const __bf16* g, __bf16* l) {
    __builtin_amdgcn_global_load_lds(
        (const __attribute__((address_space(1))) void*)g,
        (__attribute__((address_space(3))) void*)l, 16, 0, 0);
}

// ---------- manual ds_read_b128 (invisible to SIInsertWaitcnts) ----------
__device__ __forceinline__ bf16x8 dsr128(unsigned addr) {
    bf16x8 r;
    asm volatile("ds_read_b128 %0, %1" : "=v"(r) : "v"(addr));
    return r;
}

// ---------- GEMM: C[M][N] = A[M][K] * B[N][K]^T + bias[N] ----------
__global__ __launch_bounds__(512, 2) void qgemm_kernel(const __bf16* __restrict__ A,
                                                       const __bf16* __restrict__ B,
                                                       const float* __restrict__ bias,
                                                       float* __restrict__ C) {
    __shared__ __bf16 As[2][BM][BK];   // 2 x 32 KiB
    __shared__ __bf16 Bs[2][BN][BK];   // 2 x 32 KiB  (128 KiB total -> 1 block/CU)

    const int tid  = threadIdx.x;
    const int wave = tid >> 6;          // 0..7
    const int lane = tid & 63;

    // Bijective XCD remap: 16x16 tile grid; each XCD owns an 8Mx4N region.
    const int bid = blockIdx.x;
    const int xcd = bid & 7;
    const int q   = bid >> 3;                       // 0..31
    const int tm  = (xcd >> 2) * 8 + (q & 7);       // 0..15
    const int tn  = (xcd & 3) * 4 + (q >> 3);       // 0..15
    const int bm  = tm * BM;
    const int bn  = tn * BN;

    const int wm = (wave >> 2) * 128;   // wave_m in {0,1} -> 128-row half
    const int wn = (wave & 3) * 64;     // wave_n in 0..3  -> 64-col slice

    // ---- staging addressing (per wave: 16-row stripe per half, 2 issues) ----
    // lane l writes LDS (row base + l>>3, chunk l&7); source chunk pre-swizzled
    // by (l>>3)&7 == row&7 so stored chunk s of row r holds global chunk s^(r&7).
    const int srow = wave * 16 + (lane >> 3);              // 0..127 within half
    const int schk = ((lane & 7) ^ (lane >> 3)) * 8;       // pre-swizzled source
    const __bf16* agA = A + (size_t)(bm + srow) * K + schk;
    const __bf16* agB = B + (size_t)(bn + srow) * K + schk;

    auto issueA = [&](int buf, int h, int t) {
        const __bf16* g = agA + (size_t)h * 128 * K + t * BK;
        gload_lds16(g,                 &As[buf][h * 128 + wave * 16][0]);
        gload_lds16(g + (size_t)8 * K, &As[buf][h * 128 + wave * 16 + 8][0]);
    };
    auto issueB = [&](int buf, int h, int t) {
        const __bf16* g = agB + (size_t)h * 128 * K + t * BK;
        gload_lds16(g,                 &Bs[buf][h * 128 + wave * 16][0]);
        gload_lds16(g + (size_t)8 * K, &Bs[buf][h * 128 + wave * 16 + 8][0]);
    };

    // ---- fragment read addressing (32-bit LDS byte offsets) ----
    const int fl  = lane & 15;          // row-in-frag (A: m row, B: n col)
    const int fq  = lane >> 4;          // logical 16B chunk within k-slice
    const int fx7 = fl & 7;
    const unsigned ebo0 = (unsigned)(((fq)     ^ fx7) * 16);  // ks=0 byte offset
    const unsigned ebo1 = (unsigned)(((4 + fq) ^ fx7) * 16);  // ks=1 byte offset
    // row stride = BK*2 = 128 B; frag-row stride = 16*128 = 2048 B;
    // buffer stride = 256*128 = 32768 B
    const unsigned aRow = LDS_OFF(&As[0][0][0]) + (unsigned)(wm + fl) * 128u;
    const unsigned bRow = LDS_OFF(&Bs[0][0][0]) + (unsigned)(wn + fl) * 128u;

    floatx4 acc[8][4] = {};
    bf16x8 bF[4][2];

    // MFMA cluster for one m-frag pair (acc rows i0,i1) over full K=64
#define MFMA_PAIR(i0, i1, a0, a1, a2, a3)                                        \
    do {                                                                         \
        __builtin_amdgcn_s_setprio(1);                                           \
        _Pragma("unroll")                                                        \
        for (int nt = 0; nt < 4; ++nt) {                                         \
            acc[i0][nt] = __builtin_amdgcn_mfma_f32_16x16x32_bf16(               \
                a0, bF[nt][0], acc[i0][nt], 0, 0, 0);                            \
            acc[i1][nt] = __builtin_amdgcn_mfma_f32_16x16x32_bf16(               \
                a2, bF[nt][0], acc[i1][nt], 0, 0, 0);                            \
        }                                                                        \
        _Pragma("unroll")                                                        \
        for (int nt = 0; nt < 4; ++nt) {                                         \
            acc[i0][nt] = __builtin_amdgcn_mfma_f32_16x16x32_bf16(               \
                a1, bF[nt][1], acc[i0][nt], 0, 0, 0);                            \
            acc[i1][nt] = __builtin_amdgcn_mfma_f32_16x16x32_bf16(               \
                a3, bF[nt][1], acc[i1][nt], 0, 0, 0);                            \
        }                                                                        \
        __builtin_amdgcn_s_setprio(0);                                           \
    } while (0)

    // ---- prologue: tile0 A+B, tile1 B ----
    issueB(0, 0, 0); issueB(0, 1, 0);
    issueA(0, 0, 0); issueA(0, 1, 0);
    issueB(1, 0, 1); issueB(1, 1, 1);
    asm volatile("s_waitcnt vmcnt(4)"); // tile0's 8 loads landed; tile1 B in flight
    BARRIER();

    for (int t = 0; t < TILES; ++t) {
        const int b  = t & 1;
        const unsigned bs = (unsigned)b * 32768u;
        const unsigned aB = aRow + bs;

        // tile-start: all 8 B frags + A phase-0 pair
#pragma unroll
        for (int nt = 0; nt < 4; ++nt) {
            bF[nt][0] = dsr128(bRow + bs + (unsigned)(nt * 2048) + ebo0);
            bF[nt][1] = dsr128(bRow + bs + (unsigned)(nt * 2048) + ebo1);
        }
        bf16x8 x0 = dsr128(aB + ebo0);
        bf16x8 x1 = dsr128(aB + ebo1);
        bf16x8 x2 = dsr128(aB + 2048u + ebo0);
        bf16x8 x3 = dsr128(aB + 2048u + ebo1);
        if (t + 1 < TILES) { issueA(b ^ 1, 0, t + 1); issueA(b ^ 1, 1, t + 1); }
        LGKM0();                      // all reads of Bs[b] and A(p0) done
        BARRIER();                    // #1: Bs[b] region now DMA-writable
        if (t + 2 < TILES) { issueB(b, 0, t + 2); issueB(b, 1, t + 2); }
        SB();

        // p0: prefetch A(p1) under MFMA p0
        bf16x8 y0 = dsr128(aB + 4096u + ebo0);
        bf16x8 y1 = dsr128(aB + 4096u + ebo1);
        bf16x8 y2 = dsr128(aB + 4096u + 2048u + ebo0);
        bf16x8 y3 = dsr128(aB + 4096u + 2048u + ebo1);
        SB();
        MFMA_PAIR(0, 1, x0, x1, x2, x3);
        LGKM0();

        // p1: prefetch A(p2) under MFMA p1
        x0 = dsr128(aB + 8192u + ebo0);
        x1 = dsr128(aB + 8192u + ebo1);
        x2 = dsr128(aB + 8192u + 2048u + ebo0);
        x3 = dsr128(aB + 8192u + 2048u + ebo1);
        SB();
        MFMA_PAIR(2, 3, y0, y1, y2, y3);
        LGKM0();

        // p2: prefetch A(p3) under MFMA p2
        y0 = dsr128(aB + 12288u + ebo0);
        y1 = dsr128(aB + 12288u + ebo1);
        y2 = dsr128(aB + 12288u + 2048u + ebo0);
        y3 = dsr128(aB + 12288u + 2048u + ebo1);
        SB();
        MFMA_PAIR(4, 5, x0, x1, x2, x3);
        LGKM0();

        // p3: pure MFMA
        MFMA_PAIR(6, 7, y0, y1, y2, y3);
        SB();
        if (t + 2 < TILES)      asm volatile("s_waitcnt vmcnt(4)"); // A(t+1),B(t+1) landed
        else if (t + 1 < TILES) asm volatile("s_waitcnt vmcnt(0)"); // t=T-2: drain all
        BARRIER();                    // #2: publishes DMA completion cross-wave
    }

    // epilogue: C/D layout col = lane&15, row = (lane>>4)*4 + reg (verified R1)
#pragma unroll
    for (int mt = 0; mt < 8; ++mt) {
        const int row = bm + wm + mt * 16 + fq * 4;
#pragma unroll
        for (int nt = 0; nt < 4; ++nt) {
            const int col = bn + wn + nt * 16 + fl;
            const float bv = bias[col];
            float* cp = C + (size_t)row * N + col;
#pragma unroll
            for (int r = 0; r < 4; ++r)
                cp[(size_t)r * N] = acc[mt][nt][r] + bv;
        }
    }
#undef MFMA_PAIR
}

extern "C" void kernel_launch(void* const* d_in, const int* in_sizes, int n_in,
                              void* d_out, int out_size, void* d_ws, size_t ws_size,
                              hipStream_t stream) {
    const float* x    = (const float*)d_in[0];   // (4096,1024,4) fp32
    const float* w    = (const float*)d_in[1];   // (1024,1024,4) fp32
    const float* bias = (const float*)d_in[2];   // (1024,4) fp32
    float* out = (float*)d_out;                  // (4096,1024,4) fp32

    __bf16* Abf  = (__bf16*)d_ws;                                   // 32 MB
    __bf16* Wbig = (__bf16*)((char*)d_ws + (size_t)M * K * 2);      // 32 MB

    prep_kernel<<<CVT_BLOCKS + EXP_BLOCKS, 256, 0, stream>>>(x, w, Abf, Wbig);

    qgemm_kernel<<<256, 512, 0, stream>>>(Abf, Wbig, bias, out);
}